// Round 3
// baseline (1233.029 us; speedup 1.0000x reference)
//
#include <hip/hip_runtime.h>
#include <hip/hip_bf16.h>

// Problem constants (match reference setup_inputs).
#define NN    100000
#define EE    1600000
#define DD    9
#define INF   128
#define OUTF  64
#define DOUT  (DD * OUTF)   // 576

typedef __bf16 bf16x8 __attribute__((ext_vector_type(8)));
typedef float  f32x4  __attribute__((ext_vector_type(4)));
typedef unsigned short us4 __attribute__((ext_vector_type(4)));
typedef unsigned short us8 __attribute__((ext_vector_type(8)));

__device__ __forceinline__ unsigned short f32_to_bf16_rne(float f) {
    unsigned int u = __float_as_uint(f);
    unsigned int r = u + 0x7FFFu + ((u >> 16) & 1u);
    return (unsigned short)(r >> 16);
}

__device__ __forceinline__ float bf16_to_f32(unsigned short h) {
    return __uint_as_float(((unsigned int)h) << 16);
}

// ---- f32 -> bf16 bulk convert (W only) ----
__global__ __launch_bounds__(256) void cvt_bf16_kernel(
    const float* __restrict__ in, unsigned short* __restrict__ out, int n4)
{
    int i = blockIdx.x * 256 + threadIdx.x;
    if (i < n4) {
        float4 v = reinterpret_cast<const float4*>(in)[i];
        ushort4 o;
        o.x = f32_to_bf16_rne(v.x);
        o.y = f32_to_bf16_rne(v.y);
        o.z = f32_to_bf16_rne(v.z);
        o.w = f32_to_bf16_rne(v.w);
        reinterpret_cast<ushort4*>(out)[i] = o;
    }
}

// ---- Wh[n][d][o] = (feature[n]*norm[n]) . W[d][o], bf16 out ----
// grid = (ceil(N/64), 3). Block = 256 (4 waves x 16 nodes); each block
// computes 3 divisions (d = by*3 + 0..2).
// Rationale: 1D grid (1563 blocks, 9 divisions serial) was a single
// residency wave (~6 blocks/CU) with a long serial tail; grid.y=3 gives
// 4689 blocks for overlap while only 3 feature passes (feature = 51 MB,
// L3-resident, so HBM re-fetch stays small).
__global__ __launch_bounds__(256) void gemm_wh_kernel(
    const float* __restrict__ feature,          // [N][128] f32
    const unsigned short* __restrict__ Wb,      // [D][64][128] bf16
    const float* __restrict__ norm,             // [N]
    unsigned short* __restrict__ Wh)            // [N][576] bf16
{
    __shared__ unsigned short lds[64 * 136];    // 17408 B; aliased as [64][72] store buf
    const int nb   = blockIdx.x * 64;
    const int d0   = blockIdx.y * 3;
    const int tid  = threadIdx.x;
    const int wv   = tid >> 6;
    const int lane = tid & 63;
    const int quad = lane >> 4;
    const int m16  = lane & 15;

    // Phase 1: stage feature tile (coalesced), fold norm, convert to bf16
    const float* fb = feature + (size_t)nb * INF;
    #pragma unroll
    for (int it = 0; it < 4; ++it) {
        int chunk = it * 256 + tid;            // 0..1023 chunks of 8 floats
        int node = chunk >> 4;                 // 16 chunks per 128-wide row
        int seg  = chunk & 15;
        us8 o;
        if (nb + node < NN) {
            float nm = norm[nb + node];
            const float4* fp = reinterpret_cast<const float4*>(fb + (size_t)node * INF + seg * 8);
            float4 a = fp[0], b4 = fp[1];
            o[0] = f32_to_bf16_rne(a.x * nm);  o[1] = f32_to_bf16_rne(a.y * nm);
            o[2] = f32_to_bf16_rne(a.z * nm);  o[3] = f32_to_bf16_rne(a.w * nm);
            o[4] = f32_to_bf16_rne(b4.x * nm); o[5] = f32_to_bf16_rne(b4.y * nm);
            o[6] = f32_to_bf16_rne(b4.z * nm); o[7] = f32_to_bf16_rne(b4.w * nm);
        } else {
            o = us8{};
        }
        *reinterpret_cast<us8*>(&lds[node * 136 + seg * 8]) = o;
    }
    __syncthreads();

    // Phase 2: B-fragments (feature cols = nodes) -> registers, then free LDS
    bf16x8 bfrag[4];
    {
        const unsigned short* rp = &lds[(wv * 16 + m16) * 136 + quad * 8];
        #pragma unroll
        for (int k = 0; k < 4; ++k)
            bfrag[k] = *reinterpret_cast<const bf16x8*>(rp + k * 32);
    }
    __syncthreads();   // all waves done reading feature LDS -> becomes store buf

    // Phase 3: per-division MFMA + transpose-store. No syncs needed inside:
    // each wave writes/reads only its own 16 rows of the store buffer.
    #pragma unroll
    for (int dd = 0; dd < 3; ++dd) {
        const int d = d0 + dd;
        const unsigned short* wbase = Wb + (size_t)d * OUTF * INF;
        f32x4 acc[4] = {f32x4{0,0,0,0}, f32x4{0,0,0,0}, f32x4{0,0,0,0}, f32x4{0,0,0,0}};
        #pragma unroll
        for (int k = 0; k < 4; ++k) {
            #pragma unroll
            for (int f = 0; f < 4; ++f) {
                const bf16x8 afrag = *reinterpret_cast<const bf16x8*>(
                    wbase + (size_t)(f * 16 + m16) * INF + k * 32 + quad * 8);
                acc[f] = __builtin_amdgcn_mfma_f32_16x16x32_bf16(afrag, bfrag[k], acc[f], 0, 0, 0);
            }
        }
        // C frags -> LDS store buffer [64][72]
        // C/D: col = m16 (node), row = quad*4 + r (+ f*16) = channel
        {
            unsigned short* sp = &lds[(wv * 16 + m16) * 72 + quad * 4];
            #pragma unroll
            for (int f = 0; f < 4; ++f) {
                us4 p;
                p[0] = f32_to_bf16_rne(acc[f][0]);
                p[1] = f32_to_bf16_rne(acc[f][1]);
                p[2] = f32_to_bf16_rne(acc[f][2]);
                p[3] = f32_to_bf16_rne(acc[f][3]);
                *reinterpret_cast<us4*>(sp + f * 16) = p;
            }
        }
        // wave reads back its own 16 rows (in-wave LDS ordering, no sync)
        #pragma unroll
        for (int j = 0; j < 2; ++j) {
            int row = wv * 16 + j * 8 + (lane >> 3);
            int seg = lane & 7;
            us8 v = *reinterpret_cast<const us8*>(&lds[row * 72 + seg * 8]);
            int node = nb + row;
            if (node < NN)
                *reinterpret_cast<us8*>(Wh + (size_t)node * DOUT + d * OUTF + seg * 8) = v;
        }
    }
}

// ---- CSR build pass 1: histogram over dst AND per-edge rank (the atomic's
//      return value). This makes the fill pass atomic-free. ----
__global__ __launch_bounds__(256) void hist_kernel(
    const int* __restrict__ dst, int* __restrict__ count, int* __restrict__ rank)
{
    int e = blockIdx.x * 256 + threadIdx.x;
    if (e < EE) rank[e] = atomicAdd(&count[dst[e]], 1);
}

// ---- segment allocation: disjoint exclusive bases via block scan + one
//      cursor atomic. basep is IMMUTABLE after this kernel. ----
__global__ __launch_bounds__(256) void alloc_kernel(
    const int* __restrict__ count, int* __restrict__ basep, int* __restrict__ cursor)
{
    __shared__ int wtot[4];
    __shared__ int bbase;
    const int lane = threadIdx.x & 63;
    const int wv   = threadIdx.x >> 6;
    const int g = blockIdx.x * 256 + threadIdx.x;
    const int c = (g < NN) ? count[g] : 0;
    int s = c;
    #pragma unroll
    for (int o = 1; o < 64; o <<= 1) {
        int t = __shfl_up(s, o);
        if (lane >= o) s += t;
    }
    if (lane == 63) wtot[wv] = s;
    __syncthreads();
    if (threadIdx.x == 0) {
        int t0 = wtot[0], t1 = wtot[1], t2 = wtot[2], t3 = wtot[3];
        bbase = atomicAdd(cursor, t0 + t1 + t2 + t3);
        wtot[0] = 0; wtot[1] = t0; wtot[2] = t0 + t1; wtot[3] = t0 + t1 + t2;
    }
    __syncthreads();
    int base = bbase + wtot[wv] + (s - c);
    if (g < NN) basep[g] = base;
}

// ---- fill (ATOMIC-FREE): slot = basep[dst] + rank. Plain loads + one
//      scattered 4B store into the 6.4 MB payload (L2/L3 absorbs). ----
__global__ __launch_bounds__(256) void fill_kernel(
    const int* __restrict__ src, const int* __restrict__ dst,
    const int* __restrict__ ediv, const int* __restrict__ rank,
    const int* __restrict__ basep, int* __restrict__ payload)
{
    int e = blockIdx.x * 256 + threadIdx.x;
    if (e < EE) {
        int idx = basep[dst[e]] + rank[e];
        payload[idx] = (src[e] << 4) | ediv[e];
    }
}

// ---- gather v4: one wave per node; lane = channel. LDS-atomic accumulate,
// but with the round-2 latency bug fixed: loads and ds_adds are SPLIT into
// two separately-unrolled phases so the compiler issues 16 independent
// global loads back-to-back (MLP=16) before any LDS atomic (round 2
// interleaved them -> load/vmcnt(0)/ds_add serial chain, VGPR collapsed
// to 8, 535 us). Tail slots are cndmask-zeroed (no branches -- round-1's
// branch scaffolding was the other failure mode); idle readlanes give p=0
// which harmlessly loads the cached row 0 and adds 0.0f.
// Per-edge cost: ~4 VALU + 1 VMEM + 1 DS; no selection logic at all.
// LDS bank pattern (dv*64+lane)%32 = lane%32 -> 2 lanes/bank = conflict-free.
__global__ __launch_bounds__(256) void gather_kernel(
    const unsigned short* __restrict__ Wh, const int* __restrict__ payload,
    const int* __restrict__ basep, const int* __restrict__ count,
    const float* __restrict__ norm, float* __restrict__ out)
{
    __shared__ float sacc[4][DD * OUTF];    // 4 waves x 576 f32 = 9216 B
    const int wv   = threadIdx.x >> 6;
    const int lane = threadIdx.x & 63;
    const int n = blockIdx.x * 4 + wv;
    if (n >= NN) return;                    // no barriers in this kernel

    float* my = sacc[wv];
    #pragma unroll
    for (int k = 0; k < DD; ++k) my[k * OUTF + lane] = 0.0f;
    // wave-private region: no __syncthreads needed anywhere

    const int c = count[n];
    const int b = basep[n];

    for (int i0 = 0; i0 < c; i0 += 64) {
        const int take = min(c - i0, 64);
        int pv = (lane < take) ? payload[b + i0 + lane] : 0;
        for (int j = 0; j < take; j += 16) {
            const int n16 = min(take - j, 16);
            float v[16];
            int   dv[16];
            // Phase A: 16 independent loads, no atomics in between.
            #pragma unroll
            for (int u = 0; u < 16; ++u) {
                int p = __builtin_amdgcn_readlane(pv, j + u);   // 0 for idle slots
                dv[u] = p & 15;
                float x = bf16_to_f32(Wh[(size_t)(p >> 4) * DOUT + dv[u] * OUTF + lane]);
                v[u] = (u < n16) ? x : 0.0f;    // uniform scalar cond -> cndmask
            }
            // Phase B: 16 ds_add_f32 (HW-ordered RMW; +0.0 for idle slots).
            #pragma unroll
            for (int u = 0; u < 16; ++u)
                atomicAdd(&my[dv[u] * OUTF + lane], v[u]);
        }
    }

    const float nm = norm[n];
    #pragma unroll
    for (int k = 0; k < DD; ++k)
        out[(size_t)n * DOUT + k * OUTF + lane] = fmaxf(my[k * OUTF + lane] * nm, 0.0f);
}

extern "C" void kernel_launch(void* const* d_in, const int* in_sizes, int n_in,
                              void* d_out, int out_size, void* d_ws, size_t ws_size,
                              hipStream_t stream) {
    const float* feature = (const float*)d_in[0];   // [N,128]
    const float* norm    = (const float*)d_in[1];   // [N,1]
    const float* W       = (const float*)d_in[2];   // [D,64,128]
    const int*   src     = (const int*)d_in[3];     // [E]
    const int*   dst     = (const int*)d_in[4];     // [E]
    const int*   ediv    = (const int*)d_in[5];     // [E]
    float* out = (float*)d_out;                     // [N, 576]

    // Workspace layout (~129 MB, under the proven ~141 MB budget):
    //   Wh      bf16 [N][576]     @ 0            (115,200,000 B)
    //   count   int  [NN]         @ 115,200,000  (400,000 B)
    //   basep   int  [NN]         @ 115,600,000  (400,000 B)
    //   payload int  [E]          @ 116,000,000  (6,400,000 B)
    //   rank    int  [E]          @ 122,400,000  (6,400,000 B)
    //   cursor  int               @ 128,800,000  (4 B)
    //   Wb      bf16 [D][64][128] @ 128,800,064  (147,456 B)
    char* ws = (char*)d_ws;
    unsigned short* Wh = (unsigned short*)ws;
    int* count   = (int*)(ws + 115200000);
    int* basep   = (int*)(ws + 115600000);
    int* payload = (int*)(ws + 116000000);
    int* rank    = (int*)(ws + 122400000);
    int* cursor  = (int*)(ws + 128800000);
    unsigned short* Wb = (unsigned short*)(ws + 128800064);

    // 1) convert W to bf16 (tiny)
    const int nw4 = DD * OUTF * INF / 4; // 18,432
    cvt_bf16_kernel<<<(nw4 + 255) / 256, 256, 0, stream>>>(W, Wb, nw4);

    // 2) CSR build over dst bins (pass1 records rank -> fill is atomic-free)
    hipMemsetAsync(count, 0, (size_t)NN * sizeof(int), stream);
    hipMemsetAsync(cursor, 0, sizeof(int), stream);
    hist_kernel<<<(EE + 255) / 256, 256, 0, stream>>>(dst, count, rank);
    alloc_kernel<<<(NN + 255) / 256, 256, 0, stream>>>(count, basep, cursor);
    fill_kernel<<<(EE + 255) / 256, 256, 0, stream>>>(src, dst, ediv, rank, basep, payload);

    // 3) per-division projection (MFMA bf16), 3 divisions per block
    dim3 g1((NN + 63) / 64, 3);
    gemm_wh_kernel<<<g1, 256, 0, stream>>>(feature, Wb, norm, Wh);

    // 4) gather + fused dst-norm scale + relu (batched loads + LDS atomics)
    gather_kernel<<<(NN + 3) / 4, 256, 0, stream>>>(Wh, payload, basep, count, norm, out);
}

// Round 4
// 615.458 us; speedup vs baseline: 2.0034x; 2.0034x over previous
//
#include <hip/hip_runtime.h>
#include <hip/hip_bf16.h>

// Problem constants (match reference setup_inputs).
#define NN    100000
#define EE    1600000
#define DD    9
#define INF   128
#define OUTF  64
#define DOUT  (DD * OUTF)   // 576

typedef __bf16 bf16x8 __attribute__((ext_vector_type(8)));
typedef float  f32x4  __attribute__((ext_vector_type(4)));
typedef unsigned short us4 __attribute__((ext_vector_type(4)));
typedef unsigned short us8 __attribute__((ext_vector_type(8)));

__device__ __forceinline__ unsigned short f32_to_bf16_rne(float f) {
    unsigned int u = __float_as_uint(f);
    unsigned int r = u + 0x7FFFu + ((u >> 16) & 1u);
    return (unsigned short)(r >> 16);
}

__device__ __forceinline__ float bf16_to_f32(unsigned short h) {
    return __uint_as_float(((unsigned int)h) << 16);
}

// ---- f32 -> bf16 bulk convert (W only) ----
__global__ __launch_bounds__(256) void cvt_bf16_kernel(
    const float* __restrict__ in, unsigned short* __restrict__ out, int n4)
{
    int i = blockIdx.x * 256 + threadIdx.x;
    if (i < n4) {
        float4 v = reinterpret_cast<const float4*>(in)[i];
        ushort4 o;
        o.x = f32_to_bf16_rne(v.x);
        o.y = f32_to_bf16_rne(v.y);
        o.z = f32_to_bf16_rne(v.z);
        o.w = f32_to_bf16_rne(v.w);
        reinterpret_cast<ushort4*>(out)[i] = o;
    }
}

// ---- Wh[n][d][o] = (feature[n]*norm[n]) . W[d][o], bf16 out ----
// grid = (ceil(N/64), 3); each block stages its feature tile once and
// computes 3 divisions (W = 147 KB, L2-hot; feature = 51 MB, L3-resident).
__global__ __launch_bounds__(256) void gemm_wh_kernel(
    const float* __restrict__ feature,          // [N][128] f32
    const unsigned short* __restrict__ Wb,      // [D][64][128] bf16
    const float* __restrict__ norm,             // [N]
    unsigned short* __restrict__ Wh)            // [N][576] bf16
{
    __shared__ unsigned short lds[64 * 136];    // 17408 B; aliased as [64][72] store buf
    const int nb   = blockIdx.x * 64;
    const int d0   = blockIdx.y * 3;
    const int tid  = threadIdx.x;
    const int wv   = tid >> 6;
    const int lane = tid & 63;
    const int quad = lane >> 4;
    const int m16  = lane & 15;

    // Phase 1: stage feature tile (coalesced), fold norm, convert to bf16
    const float* fb = feature + (size_t)nb * INF;
    #pragma unroll
    for (int it = 0; it < 4; ++it) {
        int chunk = it * 256 + tid;            // 0..1023 chunks of 8 floats
        int node = chunk >> 4;                 // 16 chunks per 128-wide row
        int seg  = chunk & 15;
        us8 o;
        if (nb + node < NN) {
            float nm = norm[nb + node];
            const float4* fp = reinterpret_cast<const float4*>(fb + (size_t)node * INF + seg * 8);
            float4 a = fp[0], b4 = fp[1];
            o[0] = f32_to_bf16_rne(a.x * nm);  o[1] = f32_to_bf16_rne(a.y * nm);
            o[2] = f32_to_bf16_rne(a.z * nm);  o[3] = f32_to_bf16_rne(a.w * nm);
            o[4] = f32_to_bf16_rne(b4.x * nm); o[5] = f32_to_bf16_rne(b4.y * nm);
            o[6] = f32_to_bf16_rne(b4.z * nm); o[7] = f32_to_bf16_rne(b4.w * nm);
        } else {
            o = us8{};
        }
        *reinterpret_cast<us8*>(&lds[node * 136 + seg * 8]) = o;
    }
    __syncthreads();

    // Phase 2: B-fragments (feature cols = nodes) -> registers, then free LDS
    bf16x8 bfrag[4];
    {
        const unsigned short* rp = &lds[(wv * 16 + m16) * 136 + quad * 8];
        #pragma unroll
        for (int k = 0; k < 4; ++k)
            bfrag[k] = *reinterpret_cast<const bf16x8*>(rp + k * 32);
    }
    __syncthreads();   // all waves done reading feature LDS -> becomes store buf

    // Phase 3: per-division MFMA + transpose-store (wave-private rows, no sync)
    #pragma unroll
    for (int dd = 0; dd < 3; ++dd) {
        const int d = d0 + dd;
        const unsigned short* wbase = Wb + (size_t)d * OUTF * INF;
        f32x4 acc[4] = {f32x4{0,0,0,0}, f32x4{0,0,0,0}, f32x4{0,0,0,0}, f32x4{0,0,0,0}};
        #pragma unroll
        for (int k = 0; k < 4; ++k) {
            #pragma unroll
            for (int f = 0; f < 4; ++f) {
                const bf16x8 afrag = *reinterpret_cast<const bf16x8*>(
                    wbase + (size_t)(f * 16 + m16) * INF + k * 32 + quad * 8);
                acc[f] = __builtin_amdgcn_mfma_f32_16x16x32_bf16(afrag, bfrag[k], acc[f], 0, 0, 0);
            }
        }
        // C frags -> LDS store buffer [64][72]; C/D: col=m16(node), row=quad*4+r(+f*16)
        {
            unsigned short* sp = &lds[(wv * 16 + m16) * 72 + quad * 4];
            #pragma unroll
            for (int f = 0; f < 4; ++f) {
                us4 p;
                p[0] = f32_to_bf16_rne(acc[f][0]);
                p[1] = f32_to_bf16_rne(acc[f][1]);
                p[2] = f32_to_bf16_rne(acc[f][2]);
                p[3] = f32_to_bf16_rne(acc[f][3]);
                *reinterpret_cast<us4*>(sp + f * 16) = p;
            }
        }
        #pragma unroll
        for (int j = 0; j < 2; ++j) {
            int row = wv * 16 + j * 8 + (lane >> 3);
            int seg = lane & 7;
            us8 v = *reinterpret_cast<const us8*>(&lds[row * 72 + seg * 8]);
            int node = nb + row;
            if (node < NN)
                *reinterpret_cast<us8*>(Wh + (size_t)node * DOUT + d * OUTF + seg * 8) = v;
        }
    }
}

// ---- CSR pass 1: XCD-SHARDED histogram. Shard = blockIdx&7 tracks the
// round-robin block->XCD mapping, so the returning fetch-add hits a line
// that stays resident in the issuing XCD's L2 (prev: one 400KB array hit
// from all 8 XCDs -> cross-XCD line bouncing on every atomic; CSR build
// measured ~390us by cross-round subtraction). Correctness does NOT depend
// on the mapping -- any shard assignment is valid. rank packs (r<<3)|shard.
__global__ __launch_bounds__(256) void hist_kernel(
    const int* __restrict__ dst, int* __restrict__ count_s, int* __restrict__ rank)
{
    int e = blockIdx.x * 256 + threadIdx.x;
    int sh = blockIdx.x & 7;
    if (e < EE) {
        int r = atomicAdd(&count_s[sh * NN + dst[e]], 1);
        rank[e] = (r << 3) | sh;
    }
}

// ---- alloc: per-node total over 8 shards, block scan + one cursor atomic,
// then per-shard exclusive bases. basep_s immutable afterwards. ----
__global__ __launch_bounds__(256) void alloc_kernel(
    const int* __restrict__ count_s, int* __restrict__ basep_s,
    int* __restrict__ count_tot, int* __restrict__ cursor)
{
    __shared__ int wtot[4];
    __shared__ int bbase;
    const int lane = threadIdx.x & 63;
    const int wv   = threadIdx.x >> 6;
    const int g = blockIdx.x * 256 + threadIdx.x;
    int cs[8];
    int tot = 0;
    #pragma unroll
    for (int s = 0; s < 8; ++s) {
        cs[s] = (g < NN) ? count_s[s * NN + g] : 0;
        tot += cs[s];
    }
    int sc = tot;
    #pragma unroll
    for (int o = 1; o < 64; o <<= 1) {
        int t = __shfl_up(sc, o);
        if (lane >= o) sc += t;
    }
    if (lane == 63) wtot[wv] = sc;
    __syncthreads();
    if (threadIdx.x == 0) {
        int t0 = wtot[0], t1 = wtot[1], t2 = wtot[2], t3 = wtot[3];
        bbase = atomicAdd(cursor, t0 + t1 + t2 + t3);
        wtot[0] = 0; wtot[1] = t0; wtot[2] = t0 + t1; wtot[3] = t0 + t1 + t2;
    }
    __syncthreads();
    int base = bbase + wtot[wv] + (sc - tot);
    if (g < NN) {
        count_tot[g] = tot;
        int p = base;
        #pragma unroll
        for (int s = 0; s < 8; ++s) {
            basep_s[s * NN + g] = p;
            p += cs[s];
        }
    }
}

// ---- fill (atomic-free): slot = basep_s[shard][dst] + r ----
__global__ __launch_bounds__(256) void fill_kernel(
    const int* __restrict__ src, const int* __restrict__ dst,
    const int* __restrict__ ediv, const int* __restrict__ rank,
    const int* __restrict__ basep_s, int* __restrict__ payload)
{
    int e = blockIdx.x * 256 + threadIdx.x;
    if (e < EE) {
        int rk = rank[e];
        int idx = basep_s[(rk & 7) * NN + dst[e]] + (rk >> 3);
        payload[idx] = (src[e] << 4) | ediv[e];
    }
}

// ---- gather v5: round-0 structure (proven 8-deep load MLP, masked-FMA
// accumulate) with the selection moved to the SCALAR pipe. dv comes from
// readlane (wave-uniform), so the 0/1 multiplier is built with integer
// scalar ops: m = bits((0 - (dv==k && u<n8)) & 0x3f800000). The bit form
// (not 1.0f/0.0f literals) stops InstCombine rewriting fmul(select(1,0),v)
// into select(v,0)+add, which would pull it back onto the VALU; the FMA is
// then a single v_fmac acc[k], s_m, v[u]. ~10 VALU/edge vs round-0's ~60
// (round-0 VALUBusy 53% @166us => VALU-issue-bound). Tail masking is folded
// into the same scalar multiplier -> no branches, no cndmask.
// LDS atomics abandoned: rounds 2/3 proved the compiler serializes loads
// against ds_add (VGPR collapsed to 8/24, 535/775us).
__global__ __launch_bounds__(256) void gather_kernel(
    const unsigned short* __restrict__ Wh, const int* __restrict__ payload,
    const int* __restrict__ basep_s, const int* __restrict__ count_tot,
    const float* __restrict__ norm, float* __restrict__ out)
{
    const int wv   = threadIdx.x >> 6;
    const int lane = threadIdx.x & 63;
    const int n = blockIdx.x * 4 + wv;
    if (n >= NN) return;
    const int c = count_tot[n];
    const int b = basep_s[n];        // shard-0 plane == node base

    float acc[DD];
    #pragma unroll
    for (int k = 0; k < DD; ++k) acc[k] = 0.0f;

    for (int i0 = 0; i0 < c; i0 += 64) {
        const int take = min(c - i0, 64);
        int pv = (lane < take) ? payload[b + i0 + lane] : 0;
        for (int j = 0; j < take; j += 8) {
            const int n8 = min(take - j, 8);
            float v[8];
            int   dv[8];
            // Phase A: 8 independent row loads (SGPR base + lane*2 offset)
            #pragma unroll
            for (int u = 0; u < 8; ++u) {
                int p = __builtin_amdgcn_readlane(pv, j + u);   // 0 for idle slots
                dv[u] = p & 15;
                v[u] = bf16_to_f32(Wh[(size_t)(p >> 4) * DOUT + dv[u] * OUTF + lane]);
            }
            // Phase B: scalar-multiplier FMA accumulate (SALU selects, VALU fmac)
            #pragma unroll
            for (int u = 0; u < 8; ++u) {
                const unsigned tl = (unsigned)(u < n8);
                #pragma unroll
                for (int k = 0; k < DD; ++k) {
                    unsigned live = tl & (unsigned)(dv[u] == k);
                    float m = __uint_as_float((0u - live) & 0x3f800000u);
                    acc[k] += m * v[u];
                }
            }
        }
    }

    const float nm = norm[n];
    #pragma unroll
    for (int k = 0; k < DD; ++k)
        out[(size_t)n * DOUT + k * OUTF + lane] = fmaxf(acc[k] * nm, 0.0f);
}

extern "C" void kernel_launch(void* const* d_in, const int* in_sizes, int n_in,
                              void* d_out, int out_size, void* d_ws, size_t ws_size,
                              hipStream_t stream) {
    const float* feature = (const float*)d_in[0];   // [N,128]
    const float* norm    = (const float*)d_in[1];   // [N,1]
    const float* W       = (const float*)d_in[2];   // [D,64,128]
    const int*   src     = (const int*)d_in[3];     // [E]
    const int*   dst     = (const int*)d_in[4];     // [E]
    const int*   ediv    = (const int*)d_in[5];     // [E]
    float* out = (float*)d_out;                     // [N, 576]

    // Workspace layout (~135 MB, under the proven ~141 MB budget):
    //   Wh        bf16 [N][576]   @ 0            (115,200,000 B)
    //   count_s   int  [8][NN]    @ 115,200,000  (3,200,000 B)
    //   basep_s   int  [8][NN]    @ 118,400,000  (3,200,000 B)
    //   count_tot int  [NN]       @ 121,600,000  (400,000 B)
    //   payload   int  [E]        @ 122,000,000  (6,400,000 B)
    //   rank      int  [E]        @ 128,400,000  (6,400,000 B)
    //   cursor    int             @ 134,800,000  (4 B)
    //   Wb        bf16 [D][64][128] @ 134,800,064 (147,456 B)
    char* ws = (char*)d_ws;
    unsigned short* Wh = (unsigned short*)ws;
    int* count_s   = (int*)(ws + 115200000);
    int* basep_s   = (int*)(ws + 118400000);
    int* count_tot = (int*)(ws + 121600000);
    int* payload   = (int*)(ws + 122000000);
    int* rank      = (int*)(ws + 128400000);
    int* cursor    = (int*)(ws + 134800000);
    unsigned short* Wb = (unsigned short*)(ws + 134800064);

    // 1) convert W to bf16 (tiny)
    const int nw4 = DD * OUTF * INF / 4; // 18,432
    cvt_bf16_kernel<<<(nw4 + 255) / 256, 256, 0, stream>>>(W, Wb, nw4);

    // 2) CSR build (XCD-sharded histogram -> scan -> atomic-free fill)
    hipMemsetAsync(count_s, 0, (size_t)8 * NN * sizeof(int), stream);
    hipMemsetAsync(cursor, 0, sizeof(int), stream);
    hist_kernel<<<(EE + 255) / 256, 256, 0, stream>>>(dst, count_s, rank);
    alloc_kernel<<<(NN + 255) / 256, 256, 0, stream>>>(count_s, basep_s, count_tot, cursor);
    fill_kernel<<<(EE + 255) / 256, 256, 0, stream>>>(src, dst, ediv, rank, basep_s, payload);

    // 3) per-division projection (MFMA bf16), 3 divisions per block
    dim3 g1((NN + 63) / 64, 3);
    gemm_wh_kernel<<<g1, 256, 0, stream>>>(feature, Wb, norm, Wh);

    // 4) gather + fused dst-norm scale + relu
    gather_kernel<<<(NN + 3) / 4, 256, 0, stream>>>(Wh, payload, basep_s, count_tot, norm, out);
}